// Round 13
// baseline (241.396 us; speedup 1.0000x reference)
//
#include <hip/hip_runtime.h>
#include <math.h>

#define NN 50000
#define EE 600000
#define GG 250
#define HH 128

// prep_k grid split
#define B_CVT  6250
#define B_W    384
#define B_ROOT 196
#define B_ZD   196
#define B_ZH   125

typedef __attribute__((ext_vector_type(8))) short s16x8;
typedef __attribute__((ext_vector_type(8))) unsigned short u16x8;
typedef __attribute__((ext_vector_type(4))) unsigned short u16x4;
typedef __attribute__((ext_vector_type(4))) float f32x4;

__device__ __forceinline__ float b2f(unsigned short u) {
  union { unsigned int i; float f; } v; v.i = ((unsigned int)u) << 16; return v.f;
}
__device__ __forceinline__ unsigned short f2b(float f) {
  union { float f; unsigned int i; } v; v.f = f;
  unsigned int x = v.i;
  unsigned int r = (x + 0x7FFFu + ((x >> 16) & 1u)) >> 16;   // RNE, finite inputs
  return (unsigned short)r;
}

// ---------- fused prep: cvt_x | cvtW(fragment layout) | root | zero-deg | zero-hg ----------
// WT2 layout: idx = L*32768 + w*4096 + m*2048 + kk*512 + lane*8 + j
__global__ __launch_bounds__(256) void prep_k(
    const float* __restrict__ x, unsigned short* __restrict__ xb,
    const float* __restrict__ W0, const float* __restrict__ W1,
    const float* __restrict__ W2, const float* __restrict__ W3,
    const float* __restrict__ W4, const float* __restrict__ W5,
    unsigned short* __restrict__ WT,
    int* __restrict__ deg,
    const int* __restrict__ batch, int* __restrict__ root,
    float* __restrict__ hg) {
  int b = blockIdx.x, tid = threadIdx.x;
  if (b < B_CVT) {
    int i = b * 256 + tid;                       // x4 floats
    float4 v = *(const float4*)&x[i * 4];
    u16x4 o; o[0] = f2b(v.x); o[1] = f2b(v.y); o[2] = f2b(v.z); o[3] = f2b(v.w);
    *(u16x4*)&xb[i * 4] = o;
  } else if (b < B_CVT + B_W) {
    int i = (b - B_CVT) * 256 + tid;             // 0..98303
    int j = i & 7, lane = (i >> 3) & 63, kk = (i >> 9) & 3;
    int m = (i >> 11) & 1, w = (i >> 12) & 7, L = i >> 15;
    int sel = L * 2 + m;
    const float* W = (sel == 0) ? W0 : (sel == 1) ? W1 : (sel == 2) ? W2
                     : (sel == 3) ? W3 : (sel == 4) ? W4 : W5;
    int col = w * 16 + (lane & 15);
    int k = kk * 32 + ((lane >> 4) & 3) * 8 + j;
    WT[i] = f2b(W[k * 128 + col]);
  } else if (b < B_CVT + B_W + B_ROOT) {
    int n = (b - B_CVT - B_W) * 256 + tid;
    if (n < NN) {
      int bg = batch[n];
      if (n == 0 || batch[n - 1] != bg) root[bg] = n;
    }
  } else if (b < B_CVT + B_W + B_ROOT + B_ZD) {
    int n = (b - B_CVT - B_W - B_ROOT) * 256 + tid;
    if (n < NN) deg[n] = 0;
  } else {
    int i = (b - B_CVT - B_W - B_ROOT - B_ZD) * 256 + tid;   // < 32000
    hg[i] = 0.f;
  }
}

// ---------- histogram ----------
__global__ void hist_k(const int* __restrict__ dst, int* __restrict__ deg) {
  int e = blockIdx.x * 256 + threadIdx.x;
  if (e < EE) atomicAdd(&deg[dst[e]], 1);
}

// ---------- scan, phase 1 ----------
__global__ __launch_bounds__(1024) void scan1_k(const int* __restrict__ deg,
                                                int* __restrict__ excl,
                                                int* __restrict__ bsum) {
  __shared__ int sums[16];
  int tid = threadIdx.x;
  int i = blockIdx.x * 1024 + tid;
  int v = (i < NN) ? deg[i] : 0;
  int lane = tid & 63, wid = tid >> 6;
  int x = v;
  #pragma unroll
  for (int d = 1; d < 64; d <<= 1) { int y = __shfl_up(x, d); if (lane >= d) x += y; }
  if (lane == 63) sums[wid] = x;
  __syncthreads();
  if (wid == 0) {
    int s = (lane < 16) ? sums[lane] : 0;
    #pragma unroll
    for (int d = 1; d < 16; d <<= 1) { int y = __shfl_up(s, d); if (lane >= d) s += y; }
    if (lane < 16) sums[lane] = s;
  }
  __syncthreads();
  int ex = (wid ? sums[wid - 1] : 0) + x - v;
  if (i < NN) excl[i] = ex;
  if (tid == 1023) bsum[blockIdx.x] = sums[15];
}

// ---------- scan, phase 2+3 fused ----------
__global__ __launch_bounds__(256) void scanB_k(const int* __restrict__ excl,
                                               const int* __restrict__ bsum,
                                               int* __restrict__ rowptr,
                                               int* __restrict__ wp) {
  __shared__ int sboff[64];
  int tid = threadIdx.x;
  if (tid < 64) {
    int v = (tid < 49) ? bsum[tid] : 0;
    int x = v;
    #pragma unroll
    for (int d = 1; d < 64; d <<= 1) { int y = __shfl_up(x, d); if (tid >= d) x += y; }
    sboff[tid] = x - v;
  }
  __syncthreads();
  int i = blockIdx.x * 256 + tid;
  if (i < NN) {
    int r = excl[i] + sboff[i >> 10];
    rowptr[i] = r; wp[i] = r;
  }
  if (i == 0) rowptr[NN] = EE;
}

__global__ void scatter_k(const int* __restrict__ src, const int* __restrict__ dst,
                          int* __restrict__ wp, int* __restrict__ eidx) {
  int e = blockIdx.x * 256 + threadIdx.x;
  if (e < EE) {
    int p = atomicAdd(&wp[dst[e]], 1);
    eidx[p] = src[e];
  }
}

// ---------- fused layer: deep-MLP gather-mean -> LDS, MFMA, L2norm, relu ----------
// 512 threads / 8 waves / 64 rows per block. Wave w owns col-tile cc=w.
// Gather: 16 lanes/node; ONE coalesced eidx vector load per node, then up to 16
// row-loads issued back-to-back (64 loads in flight per wave).
__global__ __launch_bounds__(512) void layer_k(
    const unsigned short* __restrict__ hb,
    const int* __restrict__ rowptr, const int* __restrict__ eidx,
    const unsigned short* __restrict__ WT2, const float* __restrict__ bl,
    unsigned short* __restrict__ hout, float* __restrict__ hgmax) {
  __shared__ unsigned short sAgg[64 * 128];   // 16 KB (reused as sOut)
  __shared__ unsigned short sH[64 * 128];     // 16 KB
  __shared__ float sred[8][64];
  __shared__ float sinv[64];
  int tid = threadIdx.x;
  int r0 = blockIdx.x * 64;
  int lane = tid & 63, w = tid >> 6;
  int l16 = lane & 15, hi = lane >> 4;

  // ---- weights & bias (issue first; independent of gather) ----
  s16x8 wf[8];                                // f = m*4+kk
  #pragma unroll
  for (int f = 0; f < 8; ++f)
    wf[f] = *(const s16x8*)&WT2[w * 4096 + f * 512 + lane * 8];
  float bb = bl[w * 16 + l16];

  // ---- gather phase: 32 groups of 16 lanes, 2 nodes each ----
  {
    int gid = tid >> 4, gl = tid & 15;
    int wbase = (lane >> 4) << 4;             // group's base lane within wave
    #pragma unroll 1
    for (int s = 0; s < 2; ++s) {
      int rl = gid * 2 + s;                   // local row 0..63
      int node = r0 + rl; if (node > NN - 1) node = NN - 1;
      int st = rowptr[node], en = rowptr[node + 1];
      int deg = en - st;
      u16x8 own = *(const u16x8*)&hb[node * 128 + gl * 8];
      // one coalesced 64B eidx load covers up to 16 edges
      int myidx = 0;
      if (deg > 0) {
        int ei = st + gl; if (ei > en - 1) ei = en - 1;
        myidx = eidx[ei];
      }
      int m = deg < 16 ? deg : 16;
      u16x8 rv[16];
      #pragma unroll
      for (int t = 0; t < 16; ++t) {
        int sidx = __shfl(myidx, wbase + t);
        if (t < m) rv[t] = *(const u16x8*)&hb[sidx * 128 + gl * 8];
      }
      float acc[8] = {0.f, 0.f, 0.f, 0.f, 0.f, 0.f, 0.f, 0.f};
      // tail (deg > 16, ~10% of nodes): overlaps with in-flight rv loads
      for (int e = st + 16; e < en; ++e) {
        int sidx = eidx[e];                   // uniform in group -> broadcast
        u16x8 v = *(const u16x8*)&hb[sidx * 128 + gl * 8];
        #pragma unroll
        for (int j = 0; j < 8; ++j) acc[j] += b2f(v[j]);
      }
      #pragma unroll
      for (int t = 0; t < 16; ++t) {
        if (t < m) {
          #pragma unroll
          for (int j = 0; j < 8; ++j) acc[j] += b2f(rv[t][j]);
        }
      }
      float inv = 1.f / (float)(deg > 0 ? deg : 1);
      u16x8 o;
      #pragma unroll
      for (int j = 0; j < 8; ++j) o[j] = f2b(acc[j] * inv);
      *(u16x8*)&sAgg[rl * 128 + ((gl ^ (rl & 7)) * 8)] = o;
      *(u16x8*)&sH[rl * 128 + ((gl ^ (rl & 7)) * 8)] = own;
    }
  }
  __syncthreads();

  // ---- MFMA: 4 row-tiles x this wave's col-tile ----
  f32x4 acc[4];
  #pragma unroll
  for (int rt = 0; rt < 4; ++rt) acc[rt] = (f32x4){0.f, 0.f, 0.f, 0.f};
  #pragma unroll
  for (int kk = 0; kk < 4; ++kk) {
    int au = ((kk * 4 + hi) ^ (l16 & 7)) * 8;
    #pragma unroll
    for (int rt = 0; rt < 4; ++rt) {
      s16x8 a = *(const s16x8*)&sAgg[(rt * 16 + l16) * 128 + au];
      s16x8 h = *(const s16x8*)&sH[(rt * 16 + l16) * 128 + au];
      acc[rt] = __builtin_amdgcn_mfma_f32_16x16x32_bf16(a, wf[kk], acc[rt], 0, 0, 0);
      acc[rt] = __builtin_amdgcn_mfma_f32_16x16x32_bf16(h, wf[4 + kk], acc[rt], 0, 0, 0);
    }
  }

  // ---- bias + partial row-norm (this wave's 16 cols) ----
  float v[4][4];
  #pragma unroll
  for (int rt = 0; rt < 4; ++rt) {
    float ss[4];
    #pragma unroll
    for (int i = 0; i < 4; ++i) {
      float t = acc[rt][i] + bb;
      v[rt][i] = t;
      ss[i] = t * t;
    }
    #pragma unroll
    for (int m = 1; m < 16; m <<= 1) {
      #pragma unroll
      for (int i = 0; i < 4; ++i) ss[i] += __shfl_xor(ss[i], m);
    }
    if (l16 == 0) {
      #pragma unroll
      for (int i = 0; i < 4; ++i) sred[w][rt * 16 + hi * 4 + i] = ss[i];
    }
  }
  __syncthreads();
  if (tid < 64) {
    float s = 0.f;
    #pragma unroll
    for (int ww = 0; ww < 8; ++ww) s += sred[ww][tid];
    sinv[tid] = 1.f / fmaxf(sqrtf(s), 1e-12f);
  }
  __syncthreads();

  // ---- relu + store to sOut (swizzled 32B chunks) + fused pool (layer 3) ----
  #pragma unroll
  for (int rt = 0; rt < 4; ++rt) {
    float vm = 0.f;
    #pragma unroll
    for (int i = 0; i < 4; ++i) {
      int row = rt * 16 + hi * 4 + i;
      float r = fmaxf(v[rt][i] * sinv[row], 0.f);
      v[rt][i] = r;
      vm = fmaxf(vm, r);
      sAgg[row * 128 + ((w ^ (row & 7)) * 16) + l16] = f2b(r);
    }
    if (hgmax) {
      int rsb = r0 + rt * 16 + hi * 4;        // 4-row strips never cross graphs
      if (rsb < NN)
        atomicMax((int*)&hgmax[(rsb / 200) * 128 + w * 16 + l16], __float_as_int(vm));
    }
  }
  __syncthreads();

  // ---- coalesced read-back & store: 2KB contiguous per wave ----
  {
    int rr = tid >> 3, q = tid & 7;
    int row = r0 + rr;
    if (row < NN) {
      int sb = rr * 128 + ((q ^ (rr & 7)) * 16);
      u16x8 p0 = *(const u16x8*)&sAgg[sb];
      u16x8 p1 = *(const u16x8*)&sAgg[sb + 8];
      *(u16x8*)&hout[row * 128 + q * 16] = p0;
      *(u16x8*)&hout[row * 128 + q * 16 + 8] = p1;
    }
  }
}

// ---------- final: news + lin2 + lin3 + sigmoid ----------
__global__ __launch_bounds__(128) void final_k(
    const float* __restrict__ hg, const int* __restrict__ root,
    const float* __restrict__ x,
    const float* __restrict__ Wn, const float* __restrict__ bn,
    const float* __restrict__ W2, const float* __restrict__ b2,
    const float* __restrict__ W3, const float* __restrict__ b3,
    float* __restrict__ out) {
  __shared__ float hgr[128];
  __shared__ float xr[128];
  __shared__ float red[2];
  int g = blockIdx.x, j = threadIdx.x;
  int rt = root[g];
  hgr[j] = hg[g * HH + j];
  xr[j] = x[rt * HH + j];
  __syncthreads();
  float acc2 = b2[j];
  float accn = bn[j];
  for (int k = 0; k < 128; ++k) {
    acc2 += hgr[k] * W2[k * HH + j];
    accn += xr[k] * Wn[k * HH + j];
  }
  float c = fmaxf(acc2, 0.f) * W3[j] + fmaxf(accn, 0.f) * W3[HH + j];
  #pragma unroll
  for (int d = 1; d < 64; d <<= 1) c += __shfl_xor(c, d);
  if ((j & 63) == 0) red[j >> 6] = c;
  __syncthreads();
  if (j == 0) out[g] = 1.f / (1.f + expf(-(red[0] + red[1] + b3[0])));
}

extern "C" void kernel_launch(void* const* d_in, const int* in_sizes, int n_in,
                              void* d_out, int out_size, void* d_ws, size_t ws_size,
                              hipStream_t stream) {
  const float* x     = (const float*)d_in[0];
  const int*   adj   = (const int*)d_in[1];
  const int*   batch = (const int*)d_in[2];
  const float *W1l = (const float*)d_in[3],  *b1l = (const float*)d_in[4],  *W1r = (const float*)d_in[5];
  const float *W2l = (const float*)d_in[6],  *b2l = (const float*)d_in[7],  *W2r = (const float*)d_in[8];
  const float *W3l = (const float*)d_in[9],  *b3l = (const float*)d_in[10], *W3r = (const float*)d_in[11];
  const float *Wnews = (const float*)d_in[12], *bnews = (const float*)d_in[13];
  const float *Wlin2 = (const float*)d_in[14], *blin2 = (const float*)d_in[15];
  const float *Wlin3 = (const float*)d_in[16], *blin3 = (const float*)d_in[17];
  float* out = (float*)d_out;

  const int* srcp = adj;
  const int* dstp = adj + EE;

  char* ws = (char*)d_ws;
  size_t off = 0;
  auto alloc = [&](size_t bytes) -> void* {
    void* p = ws + off;
    off = (off + bytes + 255) & ~(size_t)255;
    return p;
  };
  int*   deg    = (int*)alloc(sizeof(int) * NN);
  int*   excl   = (int*)alloc(sizeof(int) * NN);
  int*   bsum   = (int*)alloc(sizeof(int) * 64);
  int*   rowptr = (int*)alloc(sizeof(int) * (NN + 1));
  int*   wp     = (int*)alloc(sizeof(int) * NN);
  int*   root   = (int*)alloc(sizeof(int) * GG);
  int*   eidx   = (int*)alloc(sizeof(int) * EE);
  unsigned short* WT = (unsigned short*)alloc(sizeof(short) * 6 * 128 * 128);
  unsigned short* xb = (unsigned short*)alloc(sizeof(short) * NN * HH);
  unsigned short* h1 = (unsigned short*)alloc(sizeof(short) * NN * HH);
  unsigned short* h2 = (unsigned short*)alloc(sizeof(short) * NN * HH);
  float* hg = (float*)alloc(sizeof(float) * GG * HH);
  (void)ws_size; (void)n_in; (void)in_sizes; (void)out_size;

  prep_k<<<B_CVT + B_W + B_ROOT + B_ZD + B_ZH, 256, 0, stream>>>(
      x, xb, W1l, W1r, W2l, W2r, W3l, W3r, WT, deg, batch, root, hg);
  hist_k<<<(EE + 255) / 256, 256, 0, stream>>>(dstp, deg);
  scan1_k<<<(NN + 1023) / 1024, 1024, 0, stream>>>(deg, excl, bsum);
  scanB_k<<<(NN + 255) / 256, 256, 0, stream>>>(excl, bsum, rowptr, wp);
  scatter_k<<<(EE + 255) / 256, 256, 0, stream>>>(srcp, dstp, wp, eidx);

  const int LGRID = (NN + 63) / 64;          // 782

  layer_k<<<LGRID, 512, 0, stream>>>(xb, rowptr, eidx, WT + 0 * 32768, b1l, h1, nullptr);
  layer_k<<<LGRID, 512, 0, stream>>>(h1, rowptr, eidx, WT + 1 * 32768, b2l, h2, nullptr);
  layer_k<<<LGRID, 512, 0, stream>>>(h2, rowptr, eidx, WT + 2 * 32768, b3l, h1, hg);

  final_k<<<GG, 128, 0, stream>>>(hg, root, x, Wnews, bnews,
                                  Wlin2, blin2, Wlin3, blin3, out);
}

// Round 14
// 230.156 us; speedup vs baseline: 1.0488x; 1.0488x over previous
//
#include <hip/hip_runtime.h>
#include <math.h>

#define NN 50000
#define EE 600000
#define GG 250
#define HH 128

// prep_k grid split
#define B_CVTQ 3125
#define B_W    384
#define B_ROOT 196
#define B_ZD   196
#define B_ZH   125

typedef __attribute__((ext_vector_type(8))) short s16x8;
typedef __attribute__((ext_vector_type(8))) unsigned short u16x8;
typedef __attribute__((ext_vector_type(4))) unsigned short u16x4;
typedef __attribute__((ext_vector_type(8))) signed char s8x8;
typedef __attribute__((ext_vector_type(16))) signed char s8x16;
typedef __attribute__((ext_vector_type(4))) float f32x4;

__device__ __forceinline__ float b2f(unsigned short u) {
  union { unsigned int i; float f; } v; v.i = ((unsigned int)u) << 16; return v.f;
}
__device__ __forceinline__ unsigned short f2b(float f) {
  union { float f; unsigned int i; } v; v.f = f;
  unsigned int x = v.i;
  unsigned int r = (x + 0x7FFFu + ((x >> 16) & 1u)) >> 16;   // RNE, finite inputs
  return (unsigned short)r;
}

// ---------- fused prep: quant+cvt x | cvtW(frag layout) | root | zero-deg | zero-hg ----------
__global__ __launch_bounds__(256) void prep_k(
    const float* __restrict__ x, unsigned short* __restrict__ xb,
    signed char* __restrict__ xq, float* __restrict__ xs,
    const float* __restrict__ W0, const float* __restrict__ W1,
    const float* __restrict__ W2, const float* __restrict__ W3,
    const float* __restrict__ W4, const float* __restrict__ W5,
    unsigned short* __restrict__ WT,
    int* __restrict__ deg,
    const int* __restrict__ batch, int* __restrict__ root,
    float* __restrict__ hg) {
  int b = blockIdx.x, tid = threadIdx.x;
  if (b < B_CVTQ) {                               // 16 rows/block: bf16 + int8 + scale
    int gid = tid >> 4, gl = tid & 15;
    int row = b * 16 + gid;                       // < 50000
    float4 a = *(const float4*)&x[row * 128 + gl * 8];
    float4 c = *(const float4*)&x[row * 128 + gl * 8 + 4];
    float vv[8] = {a.x, a.y, a.z, a.w, c.x, c.y, c.z, c.w};
    u16x8 ob;
    float m = 0.f;
    #pragma unroll
    for (int j = 0; j < 8; ++j) { ob[j] = f2b(vv[j]); m = fmaxf(m, fabsf(vv[j])); }
    *(u16x8*)&xb[row * 128 + gl * 8] = ob;
    #pragma unroll
    for (int d = 1; d < 16; d <<= 1) m = fmaxf(m, __shfl_xor(m, d));
    m = fmaxf(m, 1e-20f);
    float invs = 127.f / m;
    s8x8 oq;
    #pragma unroll
    for (int j = 0; j < 8; ++j) oq[j] = (signed char)__float2int_rn(vv[j] * invs);
    *(s8x8*)&xq[row * 128 + gl * 8] = oq;
    if (gl == 0) xs[row] = m / 127.f;
  } else if (b < B_CVTQ + B_W) {
    int i = (b - B_CVTQ) * 256 + tid;             // 0..98303
    int j = i & 7, lane = (i >> 3) & 63, kk = (i >> 9) & 3;
    int m = (i >> 11) & 1, w = (i >> 12) & 7, L = i >> 15;
    int sel = L * 2 + m;
    const float* W = (sel == 0) ? W0 : (sel == 1) ? W1 : (sel == 2) ? W2
                     : (sel == 3) ? W3 : (sel == 4) ? W4 : W5;
    int col = w * 16 + (lane & 15);
    int k = kk * 32 + ((lane >> 4) & 3) * 8 + j;
    WT[i] = f2b(W[k * 128 + col]);
  } else if (b < B_CVTQ + B_W + B_ROOT) {
    int n = (b - B_CVTQ - B_W) * 256 + tid;
    if (n < NN) {
      int bg = batch[n];
      if (n == 0 || batch[n - 1] != bg) root[bg] = n;
    }
  } else if (b < B_CVTQ + B_W + B_ROOT + B_ZD) {
    int n = (b - B_CVTQ - B_W - B_ROOT) * 256 + tid;
    if (n < NN) deg[n] = 0;
  } else {
    int i = (b - B_CVTQ - B_W - B_ROOT - B_ZD) * 256 + tid;   // < 32000
    hg[i] = 0.f;
  }
}

// ---------- histogram ----------
__global__ void hist_k(const int* __restrict__ dst, int* __restrict__ deg) {
  int e = blockIdx.x * 256 + threadIdx.x;
  if (e < EE) atomicAdd(&deg[dst[e]], 1);
}

// ---------- scan, phase 1 ----------
__global__ __launch_bounds__(1024) void scan1_k(const int* __restrict__ deg,
                                                int* __restrict__ excl,
                                                int* __restrict__ bsum) {
  __shared__ int sums[16];
  int tid = threadIdx.x;
  int i = blockIdx.x * 1024 + tid;
  int v = (i < NN) ? deg[i] : 0;
  int lane = tid & 63, wid = tid >> 6;
  int x = v;
  #pragma unroll
  for (int d = 1; d < 64; d <<= 1) { int y = __shfl_up(x, d); if (lane >= d) x += y; }
  if (lane == 63) sums[wid] = x;
  __syncthreads();
  if (wid == 0) {
    int s = (lane < 16) ? sums[lane] : 0;
    #pragma unroll
    for (int d = 1; d < 16; d <<= 1) { int y = __shfl_up(s, d); if (lane >= d) s += y; }
    if (lane < 16) sums[lane] = s;
  }
  __syncthreads();
  int ex = (wid ? sums[wid - 1] : 0) + x - v;
  if (i < NN) excl[i] = ex;
  if (tid == 1023) bsum[blockIdx.x] = sums[15];
}

// ---------- scan, phase 2+3 fused ----------
__global__ __launch_bounds__(256) void scanB_k(const int* __restrict__ excl,
                                               const int* __restrict__ bsum,
                                               int* __restrict__ rowptr,
                                               int* __restrict__ wp) {
  __shared__ int sboff[64];
  int tid = threadIdx.x;
  if (tid < 64) {
    int v = (tid < 49) ? bsum[tid] : 0;
    int x = v;
    #pragma unroll
    for (int d = 1; d < 64; d <<= 1) { int y = __shfl_up(x, d); if (tid >= d) x += y; }
    sboff[tid] = x - v;
  }
  __syncthreads();
  int i = blockIdx.x * 256 + tid;
  if (i < NN) {
    int r = excl[i] + sboff[i >> 10];
    rowptr[i] = r; wp[i] = r;
  }
  if (i == 0) rowptr[NN] = EE;
}

__global__ void scatter_k(const int* __restrict__ src, const int* __restrict__ dst,
                          int* __restrict__ wp, int* __restrict__ eidx) {
  int e = blockIdx.x * 256 + threadIdx.x;
  if (e < EE) {
    int p = atomicAdd(&wp[dst[e]], 1);
    eidx[p] = src[e];
  }
}

// ---------- fused layer: int8 gather-mean -> LDS, MFMA, L2norm, relu, dual store ----------
// 512 threads / 8 waves / 64 rows. Gather reads int8 rows (128B) + per-row scale;
// self path reads bf16. Outputs bf16 (next layer self) + int8+scale (next gather).
// Layer 3 passes hout=nullptr: pooling only, no stores.
__global__ __launch_bounds__(512) void layer_k(
    const unsigned short* __restrict__ hb,
    const signed char* __restrict__ hq, const float* __restrict__ hs,
    const int* __restrict__ rowptr, const int* __restrict__ eidx,
    const unsigned short* __restrict__ WT2, const float* __restrict__ bl,
    unsigned short* __restrict__ hout, signed char* __restrict__ houtq,
    float* __restrict__ houts, float* __restrict__ hgmax) {
  __shared__ unsigned short sAgg[64 * 128];   // 16 KB (reused as bf16 out)
  __shared__ unsigned short sH[64 * 128];     // 16 KB (reused as int8 out)
  __shared__ float sred[8][64];
  __shared__ float sredm[8][64];
  __shared__ float sinv[64];
  __shared__ float sqinv[64];
  int tid = threadIdx.x;
  int r0 = blockIdx.x * 64;
  int lane = tid & 63, w = tid >> 6;
  int l16 = lane & 15, hi = lane >> 4;
  bool doout = (hout != nullptr);

  // ---- weights & bias (issue first) ----
  s16x8 wf[8];
  #pragma unroll
  for (int f = 0; f < 8; ++f)
    wf[f] = *(const s16x8*)&WT2[w * 4096 + f * 512 + lane * 8];
  float bb = bl[w * 16 + l16];

  // ---- gather phase: 32 groups of 16 lanes, 2 nodes each (R12 structure, int8) ----
  {
    int gid = tid >> 4, gl = tid & 15;
    #pragma unroll 1
    for (int s = 0; s < 2; ++s) {
      int rl = gid * 2 + s;
      int node = r0 + rl; if (node > NN - 1) node = NN - 1;
      int st = rowptr[node], en = rowptr[node + 1];
      u16x8 own = *(const u16x8*)&hb[node * 128 + gl * 8];
      *(u16x8*)&sH[rl * 128 + ((gl ^ (rl & 7)) * 8)] = own;
      float acc[8] = {0.f, 0.f, 0.f, 0.f, 0.f, 0.f, 0.f, 0.f};
      for (int e = st; e < en; e += 4) {
        int e1 = e + 1 < en ? e + 1 : en - 1;
        int e2 = e + 2 < en ? e + 2 : en - 1;
        int e3 = e + 3 < en ? e + 3 : en - 1;
        int s0 = eidx[e], s1 = eidx[e1], s2 = eidx[e2], s3 = eidx[e3];
        s8x8 v0 = *(const s8x8*)&hq[s0 * 128 + gl * 8];
        s8x8 v1 = *(const s8x8*)&hq[s1 * 128 + gl * 8];
        s8x8 v2 = *(const s8x8*)&hq[s2 * 128 + gl * 8];
        s8x8 v3 = *(const s8x8*)&hq[s3 * 128 + gl * 8];
        float sc0 = hs[s0];
        float sc1 = (e + 1 < en) ? hs[s1] : 0.f;
        float sc2 = (e + 2 < en) ? hs[s2] : 0.f;
        float sc3 = (e + 3 < en) ? hs[s3] : 0.f;
        #pragma unroll
        for (int j = 0; j < 8; ++j) {
          acc[j] += (float)v0[j] * sc0;
          acc[j] += (float)v1[j] * sc1;
          acc[j] += (float)v2[j] * sc2;
          acc[j] += (float)v3[j] * sc3;
        }
      }
      int cnt = en - st;
      float inv = 1.f / (float)(cnt > 0 ? cnt : 1);
      u16x8 o;
      #pragma unroll
      for (int j = 0; j < 8; ++j) o[j] = f2b(acc[j] * inv);
      *(u16x8*)&sAgg[rl * 128 + ((gl ^ (rl & 7)) * 8)] = o;
    }
  }
  __syncthreads();

  // ---- MFMA: 4 row-tiles x this wave's col-tile ----
  f32x4 acc[4];
  #pragma unroll
  for (int rt = 0; rt < 4; ++rt) acc[rt] = (f32x4){0.f, 0.f, 0.f, 0.f};
  #pragma unroll
  for (int kk = 0; kk < 4; ++kk) {
    int au = ((kk * 4 + hi) ^ (l16 & 7)) * 8;
    #pragma unroll
    for (int rt = 0; rt < 4; ++rt) {
      s16x8 a = *(const s16x8*)&sAgg[(rt * 16 + l16) * 128 + au];
      s16x8 h = *(const s16x8*)&sH[(rt * 16 + l16) * 128 + au];
      acc[rt] = __builtin_amdgcn_mfma_f32_16x16x32_bf16(a, wf[kk], acc[rt], 0, 0, 0);
      acc[rt] = __builtin_amdgcn_mfma_f32_16x16x32_bf16(h, wf[4 + kk], acc[rt], 0, 0, 0);
    }
  }

  // ---- bias + partial row-norm + partial row-max (this wave's 16 cols) ----
  float v[4][4];
  #pragma unroll
  for (int rt = 0; rt < 4; ++rt) {
    float ss[4], mx[4];
    #pragma unroll
    for (int i = 0; i < 4; ++i) {
      float t = acc[rt][i] + bb;
      v[rt][i] = t;
      ss[i] = t * t;
      mx[i] = t;
    }
    #pragma unroll
    for (int m = 1; m < 16; m <<= 1) {
      #pragma unroll
      for (int i = 0; i < 4; ++i) {
        ss[i] += __shfl_xor(ss[i], m);
        mx[i] = fmaxf(mx[i], __shfl_xor(mx[i], m));
      }
    }
    if (l16 == 0) {
      #pragma unroll
      for (int i = 0; i < 4; ++i) {
        sred[w][rt * 16 + hi * 4 + i] = ss[i];
        sredm[w][rt * 16 + hi * 4 + i] = mx[i];
      }
    }
  }
  __syncthreads();
  if (tid < 64) {
    float s = 0.f, mx = -1e30f;
    #pragma unroll
    for (int ww = 0; ww < 8; ++ww) {
      s += sred[ww][tid];
      mx = fmaxf(mx, sredm[ww][tid]);
    }
    float inv = 1.f / fmaxf(sqrtf(s), 1e-12f);
    sinv[tid] = inv;
    float rs = fmaxf(fmaxf(mx, 0.f) * inv, 1e-20f);   // post-relu row max
    sqinv[tid] = 127.f / rs;
    if (doout && r0 + tid < NN) houts[r0 + tid] = rs / 127.f;
  }
  __syncthreads();

  // ---- relu + dual LDS store + fused pool (layer 3) ----
  signed char* sQ = (signed char*)sH;
  #pragma unroll
  for (int rt = 0; rt < 4; ++rt) {
    float vm = 0.f;
    #pragma unroll
    for (int i = 0; i < 4; ++i) {
      int row = rt * 16 + hi * 4 + i;
      float r = fmaxf(v[rt][i] * sinv[row], 0.f);
      vm = fmaxf(vm, r);
      if (doout) {
        sAgg[row * 128 + ((w ^ (row & 7)) * 16) + l16] = f2b(r);
        sQ[row * 128 + ((w ^ (row & 7)) * 16) + l16] =
            (signed char)__float2int_rn(r * sqinv[row]);
      }
    }
    if (hgmax) {
      int rsb = r0 + rt * 16 + hi * 4;          // 4-row strips never cross graphs
      if (rsb < NN)
        atomicMax((int*)&hgmax[(rsb / 200) * 128 + w * 16 + l16], __float_as_int(vm));
    }
  }
  if (!doout) return;
  __syncthreads();

  // ---- coalesced read-back & store ----
  {
    int rr = tid >> 3, q = tid & 7;
    int row = r0 + rr;
    if (row < NN) {
      int sb = rr * 128 + ((q ^ (rr & 7)) * 16);
      u16x8 p0 = *(const u16x8*)&sAgg[sb];
      u16x8 p1 = *(const u16x8*)&sAgg[sb + 8];
      *(u16x8*)&hout[row * 128 + q * 16] = p0;
      *(u16x8*)&hout[row * 128 + q * 16 + 8] = p1;
    }
    // int8: 64 rows x 128B; threads 0..511 cover with 16B each
    int rr2 = tid >> 3, q2 = tid & 7;
    int row2 = r0 + rr2;
    if (row2 < NN && q2 < 8) {
      int sb2 = rr2 * 128 + ((q2 ^ (rr2 & 7)) * 16);
      s8x16 pq = *(const s8x16*)&sQ[sb2];
      *(s8x16*)&houtq[row2 * 128 + q2 * 16] = pq;
    }
  }
}

// ---------- final: news + lin2 + lin3 + sigmoid ----------
__global__ __launch_bounds__(128) void final_k(
    const float* __restrict__ hg, const int* __restrict__ root,
    const float* __restrict__ x,
    const float* __restrict__ Wn, const float* __restrict__ bn,
    const float* __restrict__ W2, const float* __restrict__ b2,
    const float* __restrict__ W3, const float* __restrict__ b3,
    float* __restrict__ out) {
  __shared__ float hgr[128];
  __shared__ float xr[128];
  __shared__ float red[2];
  int g = blockIdx.x, j = threadIdx.x;
  int rt = root[g];
  hgr[j] = hg[g * HH + j];
  xr[j] = x[rt * HH + j];
  __syncthreads();
  float acc2 = b2[j];
  float accn = bn[j];
  for (int k = 0; k < 128; ++k) {
    acc2 += hgr[k] * W2[k * HH + j];
    accn += xr[k] * Wn[k * HH + j];
  }
  float c = fmaxf(acc2, 0.f) * W3[j] + fmaxf(accn, 0.f) * W3[HH + j];
  #pragma unroll
  for (int d = 1; d < 64; d <<= 1) c += __shfl_xor(c, d);
  if ((j & 63) == 0) red[j >> 6] = c;
  __syncthreads();
  if (j == 0) out[g] = 1.f / (1.f + expf(-(red[0] + red[1] + b3[0])));
}

extern "C" void kernel_launch(void* const* d_in, const int* in_sizes, int n_in,
                              void* d_out, int out_size, void* d_ws, size_t ws_size,
                              hipStream_t stream) {
  const float* x     = (const float*)d_in[0];
  const int*   adj   = (const int*)d_in[1];
  const int*   batch = (const int*)d_in[2];
  const float *W1l = (const float*)d_in[3],  *b1l = (const float*)d_in[4],  *W1r = (const float*)d_in[5];
  const float *W2l = (const float*)d_in[6],  *b2l = (const float*)d_in[7],  *W2r = (const float*)d_in[8];
  const float *W3l = (const float*)d_in[9],  *b3l = (const float*)d_in[10], *W3r = (const float*)d_in[11];
  const float *Wnews = (const float*)d_in[12], *bnews = (const float*)d_in[13];
  const float *Wlin2 = (const float*)d_in[14], *blin2 = (const float*)d_in[15];
  const float *Wlin3 = (const float*)d_in[16], *blin3 = (const float*)d_in[17];
  float* out = (float*)d_out;

  const int* srcp = adj;
  const int* dstp = adj + EE;

  char* ws = (char*)d_ws;
  size_t off = 0;
  auto alloc = [&](size_t bytes) -> void* {
    void* p = ws + off;
    off = (off + bytes + 255) & ~(size_t)255;
    return p;
  };
  int*   deg    = (int*)alloc(sizeof(int) * NN);
  int*   excl   = (int*)alloc(sizeof(int) * NN);
  int*   bsum   = (int*)alloc(sizeof(int) * 64);
  int*   rowptr = (int*)alloc(sizeof(int) * (NN + 1));
  int*   wp     = (int*)alloc(sizeof(int) * NN);
  int*   root   = (int*)alloc(sizeof(int) * GG);
  int*   eidx   = (int*)alloc(sizeof(int) * EE);
  unsigned short* WT = (unsigned short*)alloc(sizeof(short) * 6 * 128 * 128);
  unsigned short* xb = (unsigned short*)alloc(sizeof(short) * NN * HH);
  unsigned short* h1 = (unsigned short*)alloc(sizeof(short) * NN * HH);
  unsigned short* h2 = (unsigned short*)alloc(sizeof(short) * NN * HH);
  signed char* xq = (signed char*)alloc(NN * HH);
  signed char* q1 = (signed char*)alloc(NN * HH);
  signed char* q2 = (signed char*)alloc(NN * HH);
  float* xsc = (float*)alloc(sizeof(float) * NN);
  float* s1  = (float*)alloc(sizeof(float) * NN);
  float* s2  = (float*)alloc(sizeof(float) * NN);
  float* hg  = (float*)alloc(sizeof(float) * GG * HH);
  (void)ws_size; (void)n_in; (void)in_sizes; (void)out_size;

  prep_k<<<B_CVTQ + B_W + B_ROOT + B_ZD + B_ZH, 256, 0, stream>>>(
      x, xb, xq, xsc, W1l, W1r, W2l, W2r, W3l, W3r, WT, deg, batch, root, hg);
  hist_k<<<(EE + 255) / 256, 256, 0, stream>>>(dstp, deg);
  scan1_k<<<(NN + 1023) / 1024, 1024, 0, stream>>>(deg, excl, bsum);
  scanB_k<<<(NN + 255) / 256, 256, 0, stream>>>(excl, bsum, rowptr, wp);
  scatter_k<<<(EE + 255) / 256, 256, 0, stream>>>(srcp, dstp, wp, eidx);

  const int LGRID = (NN + 63) / 64;          // 782

  layer_k<<<LGRID, 512, 0, stream>>>(xb, xq, xsc, rowptr, eidx,
                                     WT + 0 * 32768, b1l, h1, q1, s1, nullptr);
  layer_k<<<LGRID, 512, 0, stream>>>(h1, q1, s1, rowptr, eidx,
                                     WT + 1 * 32768, b2l, h2, q2, s2, nullptr);
  layer_k<<<LGRID, 512, 0, stream>>>(h2, q2, s2, rowptr, eidx,
                                     WT + 2 * 32768, b3l, nullptr, nullptr, nullptr, hg);

  final_k<<<GG, 128, 0, stream>>>(hg, root, x, Wnews, bnews,
                                  Wlin2, blin2, Wlin3, blin3, out);
}

// Round 15
// 209.749 us; speedup vs baseline: 1.1509x; 1.0973x over previous
//
#include <hip/hip_runtime.h>
#include <math.h>

#define NN 50000
#define EE 600000
#define GG 250
#define HH 128

// prep_k grid split
#define B_CVT  6250
#define B_W    384
#define B_ROOT 196
#define B_ZD   196
#define B_ZH   125

typedef __attribute__((ext_vector_type(8))) short s16x8;
typedef __attribute__((ext_vector_type(8))) unsigned short u16x8;
typedef __attribute__((ext_vector_type(4))) unsigned short u16x4;
typedef __attribute__((ext_vector_type(4))) float f32x4;

__device__ __forceinline__ float b2f(unsigned short u) {
  union { unsigned int i; float f; } v; v.i = ((unsigned int)u) << 16; return v.f;
}
__device__ __forceinline__ unsigned short f2b(float f) {
  union { float f; unsigned int i; } v; v.f = f;
  unsigned int x = v.i;
  unsigned int r = (x + 0x7FFFu + ((x >> 16) & 1u)) >> 16;   // RNE, finite inputs
  return (unsigned short)r;
}

// ---------- fused prep: cvt_x | cvtW(fragment layout) | root | zero-deg | zero-hg ----------
// WT2 layout: idx = L*32768 + w*4096 + m*2048 + kk*512 + lane*8 + j
__global__ __launch_bounds__(256) void prep_k(
    const float* __restrict__ x, unsigned short* __restrict__ xb,
    const float* __restrict__ W0, const float* __restrict__ W1,
    const float* __restrict__ W2, const float* __restrict__ W3,
    const float* __restrict__ W4, const float* __restrict__ W5,
    unsigned short* __restrict__ WT,
    int* __restrict__ deg,
    const int* __restrict__ batch, int* __restrict__ root,
    float* __restrict__ hg) {
  int b = blockIdx.x, tid = threadIdx.x;
  if (b < B_CVT) {
    int i = b * 256 + tid;                       // x4 floats
    float4 v = *(const float4*)&x[i * 4];
    u16x4 o; o[0] = f2b(v.x); o[1] = f2b(v.y); o[2] = f2b(v.z); o[3] = f2b(v.w);
    *(u16x4*)&xb[i * 4] = o;
  } else if (b < B_CVT + B_W) {
    int i = (b - B_CVT) * 256 + tid;             // 0..98303
    int j = i & 7, lane = (i >> 3) & 63, kk = (i >> 9) & 3;
    int m = (i >> 11) & 1, w = (i >> 12) & 7, L = i >> 15;
    int sel = L * 2 + m;
    const float* W = (sel == 0) ? W0 : (sel == 1) ? W1 : (sel == 2) ? W2
                     : (sel == 3) ? W3 : (sel == 4) ? W4 : W5;
    int col = w * 16 + (lane & 15);
    int k = kk * 32 + ((lane >> 4) & 3) * 8 + j;
    WT[i] = f2b(W[k * 128 + col]);
  } else if (b < B_CVT + B_W + B_ROOT) {
    int n = (b - B_CVT - B_W) * 256 + tid;
    if (n < NN) {
      int bg = batch[n];
      if (n == 0 || batch[n - 1] != bg) root[bg] = n;
    }
  } else if (b < B_CVT + B_W + B_ROOT + B_ZD) {
    int n = (b - B_CVT - B_W - B_ROOT) * 256 + tid;
    if (n < NN) deg[n] = 0;
  } else {
    int i = (b - B_CVT - B_W - B_ROOT - B_ZD) * 256 + tid;   // < 32000
    hg[i] = 0.f;
  }
}

// ---------- histogram ----------
__global__ void hist_k(const int* __restrict__ dst, int* __restrict__ deg) {
  int e = blockIdx.x * 256 + threadIdx.x;
  if (e < EE) atomicAdd(&deg[dst[e]], 1);
}

// ---------- scan, phase 1 ----------
__global__ __launch_bounds__(1024) void scan1_k(const int* __restrict__ deg,
                                                int* __restrict__ excl,
                                                int* __restrict__ bsum) {
  __shared__ int sums[16];
  int tid = threadIdx.x;
  int i = blockIdx.x * 1024 + tid;
  int v = (i < NN) ? deg[i] : 0;
  int lane = tid & 63, wid = tid >> 6;
  int x = v;
  #pragma unroll
  for (int d = 1; d < 64; d <<= 1) { int y = __shfl_up(x, d); if (lane >= d) x += y; }
  if (lane == 63) sums[wid] = x;
  __syncthreads();
  if (wid == 0) {
    int s = (lane < 16) ? sums[lane] : 0;
    #pragma unroll
    for (int d = 1; d < 16; d <<= 1) { int y = __shfl_up(s, d); if (lane >= d) s += y; }
    if (lane < 16) sums[lane] = s;
  }
  __syncthreads();
  int ex = (wid ? sums[wid - 1] : 0) + x - v;
  if (i < NN) excl[i] = ex;
  if (tid == 1023) bsum[blockIdx.x] = sums[15];
}

// ---------- scan, phase 2+3 fused ----------
__global__ __launch_bounds__(256) void scanB_k(const int* __restrict__ excl,
                                               const int* __restrict__ bsum,
                                               int* __restrict__ rowptr,
                                               int* __restrict__ wp) {
  __shared__ int sboff[64];
  int tid = threadIdx.x;
  if (tid < 64) {
    int v = (tid < 49) ? bsum[tid] : 0;
    int x = v;
    #pragma unroll
    for (int d = 1; d < 64; d <<= 1) { int y = __shfl_up(x, d); if (tid >= d) x += y; }
    sboff[tid] = x - v;
  }
  __syncthreads();
  int i = blockIdx.x * 256 + tid;
  if (i < NN) {
    int r = excl[i] + sboff[i >> 10];
    rowptr[i] = r; wp[i] = r;
  }
  if (i == 0) rowptr[NN] = EE;
}

__global__ void scatter_k(const int* __restrict__ src, const int* __restrict__ dst,
                          int* __restrict__ wp, int* __restrict__ eidx) {
  int e = blockIdx.x * 256 + threadIdx.x;
  if (e < EE) {
    int p = atomicAdd(&wp[dst[e]], 1);
    eidx[p] = src[e];
  }
}

// ---------- mean aggregation (split, max-occupancy): 16 lanes/node, 8-deep ----------
__global__ __launch_bounds__(256) void agg_k(const unsigned short* __restrict__ hb,
                                             const int* __restrict__ rowptr,
                                             const int* __restrict__ eidx,
                                             unsigned short* __restrict__ aggb) {
  int lane = threadIdx.x & 63, wid = threadIdx.x >> 6;
  int sub = lane >> 4, l16 = lane & 15;
  int base = sub * 16;                       // group's base lane in wave
  int node = blockIdx.x * 16 + wid * 4 + sub;
  int start = rowptr[node], end = rowptr[node + 1];
  float acc[8] = {0.f, 0.f, 0.f, 0.f, 0.f, 0.f, 0.f, 0.f};
  for (int c = start; c < end; c += 8) {
    // one coalesced eidx load covers 8 edges (lanes 8-15 mirror 0-7)
    int ecl = c + (l16 & 7); if (ecl > end - 1) ecl = end - 1;
    int myidx = eidx[ecl];
    int s[8];
    #pragma unroll
    for (int t = 0; t < 8; ++t) s[t] = __shfl(myidx, base + t);
    u16x8 rv[8];
    #pragma unroll
    for (int t = 0; t < 8; ++t)
      rv[t] = *(const u16x8*)&hb[s[t] * HH + l16 * 8];   // always issued, clamped idx
    #pragma unroll
    for (int t = 0; t < 8; ++t) {
      if (c + t < end) {
        #pragma unroll
        for (int j = 0; j < 8; ++j) acc[j] += b2f(rv[t][j]);
      }
    }
  }
  int cnt = end - start;
  float inv = 1.f / (float)(cnt > 0 ? cnt : 1);
  u16x8 o;
  #pragma unroll
  for (int j = 0; j < 8; ++j) o[j] = f2b(acc[j] * inv);
  *(u16x8*)&aggb[node * HH + l16 * 8] = o;
}

// ---------- GEMM layer: stream aggb+hb -> LDS, MFMA, L2norm, relu, coalesced store ----------
// 512 threads / 8 waves / 64 rows per block. Wave w owns col-tile cc=w.
// Weights: 8 frags/lane in registers from coalesced WT2 layout.
// Layer 3: hout=nullptr -> pool only, no hout store.
__global__ __launch_bounds__(512) void layer_k(
    const unsigned short* __restrict__ aggb, const unsigned short* __restrict__ hb,
    const unsigned short* __restrict__ WT2, const float* __restrict__ bl,
    unsigned short* __restrict__ hout, float* __restrict__ hgmax) {
  __shared__ unsigned short sAgg[64 * 128];   // 16 KB (reused as sOut)
  __shared__ unsigned short sH[64 * 128];     // 16 KB
  __shared__ float sred[8][64];
  __shared__ float sinv[64];
  int tid = threadIdx.x;
  int r0 = blockIdx.x * 64;
  int lane = tid & 63, w = tid >> 6;
  int l16 = lane & 15, hi = lane >> 4;
  bool doout = (hout != nullptr);

  // ---- weights & bias ----
  s16x8 wf[8];                                // f = m*4+kk
  #pragma unroll
  for (int f = 0; f < 8; ++f)
    wf[f] = *(const s16x8*)&WT2[w * 4096 + f * 512 + lane * 8];
  float bb = bl[w * 16 + l16];

  // ---- stage 64x128 tiles: fully coalesced 16B/lane streams, swizzled LDS dest ----
  #pragma unroll
  for (int it = 0; it < 2; ++it) {
    int u = it * 512 + tid;                   // 16B unit id, 0..1023
    int srow = u >> 4, sunit = u & 15;
    int goff = r0 * 128 + u * 8;              // may over-read past NN (within ws)
    u16x8 va = *(const u16x8*)&aggb[goff];
    u16x8 vh = *(const u16x8*)&hb[goff];
    int sdst = srow * 128 + ((sunit ^ (srow & 7)) * 8);
    *(u16x8*)&sAgg[sdst] = va;
    *(u16x8*)&sH[sdst] = vh;
  }
  __syncthreads();

  // ---- MFMA: 4 row-tiles x this wave's col-tile ----
  f32x4 acc[4];
  #pragma unroll
  for (int rt = 0; rt < 4; ++rt) acc[rt] = (f32x4){0.f, 0.f, 0.f, 0.f};
  #pragma unroll
  for (int kk = 0; kk < 4; ++kk) {
    int au = ((kk * 4 + hi) ^ (l16 & 7)) * 8;
    #pragma unroll
    for (int rt = 0; rt < 4; ++rt) {
      s16x8 a = *(const s16x8*)&sAgg[(rt * 16 + l16) * 128 + au];
      s16x8 h = *(const s16x8*)&sH[(rt * 16 + l16) * 128 + au];
      acc[rt] = __builtin_amdgcn_mfma_f32_16x16x32_bf16(a, wf[kk], acc[rt], 0, 0, 0);
      acc[rt] = __builtin_amdgcn_mfma_f32_16x16x32_bf16(h, wf[4 + kk], acc[rt], 0, 0, 0);
    }
  }

  // ---- bias + partial row-norm (this wave's 16 cols) ----
  float v[4][4];
  #pragma unroll
  for (int rt = 0; rt < 4; ++rt) {
    float ss[4];
    #pragma unroll
    for (int i = 0; i < 4; ++i) {
      float t = acc[rt][i] + bb;
      v[rt][i] = t;
      ss[i] = t * t;
    }
    #pragma unroll
    for (int m = 1; m < 16; m <<= 1) {
      #pragma unroll
      for (int i = 0; i < 4; ++i) ss[i] += __shfl_xor(ss[i], m);
    }
    if (l16 == 0) {
      #pragma unroll
      for (int i = 0; i < 4; ++i) sred[w][rt * 16 + hi * 4 + i] = ss[i];
    }
  }
  __syncthreads();
  if (tid < 64) {
    float s = 0.f;
    #pragma unroll
    for (int ww = 0; ww < 8; ++ww) s += sred[ww][tid];
    sinv[tid] = 1.f / fmaxf(sqrtf(s), 1e-12f);
  }
  __syncthreads();

  // ---- relu + store to sOut (swizzled 32B chunks) + fused pool (layer 3) ----
  #pragma unroll
  for (int rt = 0; rt < 4; ++rt) {
    float vm = 0.f;
    #pragma unroll
    for (int i = 0; i < 4; ++i) {
      int row = rt * 16 + hi * 4 + i;
      float r = fmaxf(v[rt][i] * sinv[row], 0.f);
      vm = fmaxf(vm, r);
      if (doout) sAgg[row * 128 + ((w ^ (row & 7)) * 16) + l16] = f2b(r);
    }
    if (hgmax) {
      int rsb = r0 + rt * 16 + hi * 4;        // 4-row strips never cross graphs
      if (rsb < NN)
        atomicMax((int*)&hgmax[(rsb / 200) * 128 + w * 16 + l16], __float_as_int(vm));
    }
  }
  if (!doout) return;
  __syncthreads();

  // ---- coalesced read-back & store: 16B/lane contiguous ----
  {
    int rr = tid >> 3, q = tid & 7;
    int row = r0 + rr;
    if (row < NN) {
      int sb = rr * 128 + ((q ^ (rr & 7)) * 16);
      u16x8 p0 = *(const u16x8*)&sAgg[sb];
      u16x8 p1 = *(const u16x8*)&sAgg[sb + 8];
      *(u16x8*)&hout[row * 128 + q * 16] = p0;
      *(u16x8*)&hout[row * 128 + q * 16 + 8] = p1;
    }
  }
}

// ---------- final: news + lin2 + lin3 + sigmoid ----------
__global__ __launch_bounds__(128) void final_k(
    const float* __restrict__ hg, const int* __restrict__ root,
    const float* __restrict__ x,
    const float* __restrict__ Wn, const float* __restrict__ bn,
    const float* __restrict__ W2, const float* __restrict__ b2,
    const float* __restrict__ W3, const float* __restrict__ b3,
    float* __restrict__ out) {
  __shared__ float hgr[128];
  __shared__ float xr[128];
  __shared__ float red[2];
  int g = blockIdx.x, j = threadIdx.x;
  int rt = root[g];
  hgr[j] = hg[g * HH + j];
  xr[j] = x[rt * HH + j];
  __syncthreads();
  float acc2 = b2[j];
  float accn = bn[j];
  for (int k = 0; k < 128; ++k) {
    acc2 += hgr[k] * W2[k * HH + j];
    accn += xr[k] * Wn[k * HH + j];
  }
  float c = fmaxf(acc2, 0.f) * W3[j] + fmaxf(accn, 0.f) * W3[HH + j];
  #pragma unroll
  for (int d = 1; d < 64; d <<= 1) c += __shfl_xor(c, d);
  if ((j & 63) == 0) red[j >> 6] = c;
  __syncthreads();
  if (j == 0) out[g] = 1.f / (1.f + expf(-(red[0] + red[1] + b3[0])));
}

extern "C" void kernel_launch(void* const* d_in, const int* in_sizes, int n_in,
                              void* d_out, int out_size, void* d_ws, size_t ws_size,
                              hipStream_t stream) {
  const float* x     = (const float*)d_in[0];
  const int*   adj   = (const int*)d_in[1];
  const int*   batch = (const int*)d_in[2];
  const float *W1l = (const float*)d_in[3],  *b1l = (const float*)d_in[4],  *W1r = (const float*)d_in[5];
  const float *W2l = (const float*)d_in[6],  *b2l = (const float*)d_in[7],  *W2r = (const float*)d_in[8];
  const float *W3l = (const float*)d_in[9],  *b3l = (const float*)d_in[10], *W3r = (const float*)d_in[11];
  const float *Wnews = (const float*)d_in[12], *bnews = (const float*)d_in[13];
  const float *Wlin2 = (const float*)d_in[14], *blin2 = (const float*)d_in[15];
  const float *Wlin3 = (const float*)d_in[16], *blin3 = (const float*)d_in[17];
  float* out = (float*)d_out;

  const int* srcp = adj;
  const int* dstp = adj + EE;

  char* ws = (char*)d_ws;
  size_t off = 0;
  auto alloc = [&](size_t bytes) -> void* {
    void* p = ws + off;
    off = (off + bytes + 255) & ~(size_t)255;
    return p;
  };
  int*   deg    = (int*)alloc(sizeof(int) * NN);
  int*   excl   = (int*)alloc(sizeof(int) * NN);
  int*   bsum   = (int*)alloc(sizeof(int) * 64);
  int*   rowptr = (int*)alloc(sizeof(int) * (NN + 1));
  int*   wp     = (int*)alloc(sizeof(int) * NN);
  int*   root   = (int*)alloc(sizeof(int) * GG);
  int*   eidx   = (int*)alloc(sizeof(int) * EE);
  unsigned short* WT   = (unsigned short*)alloc(sizeof(short) * 6 * 128 * 128);
  unsigned short* xb   = (unsigned short*)alloc(sizeof(short) * NN * HH);
  unsigned short* aggb = (unsigned short*)alloc(sizeof(short) * NN * HH);
  unsigned short* h1   = (unsigned short*)alloc(sizeof(short) * NN * HH);
  unsigned short* h2   = (unsigned short*)alloc(sizeof(short) * NN * HH);
  float* hg = (float*)alloc(sizeof(float) * GG * HH);
  (void)ws_size; (void)n_in; (void)in_sizes; (void)out_size;

  prep_k<<<B_CVT + B_W + B_ROOT + B_ZD + B_ZH, 256, 0, stream>>>(
      x, xb, W1l, W1r, W2l, W2r, W3l, W3r, WT, deg, batch, root, hg);
  hist_k<<<(EE + 255) / 256, 256, 0, stream>>>(dstp, deg);
  scan1_k<<<(NN + 1023) / 1024, 1024, 0, stream>>>(deg, excl, bsum);
  scanB_k<<<(NN + 255) / 256, 256, 0, stream>>>(excl, bsum, rowptr, wp);
  scatter_k<<<(EE + 255) / 256, 256, 0, stream>>>(srcp, dstp, wp, eidx);

  const int AGG_GRID = NN / 16;              // 3125
  const int LGRID = (NN + 63) / 64;          // 782

  agg_k<<<AGG_GRID, 256, 0, stream>>>(xb, rowptr, eidx, aggb);
  layer_k<<<LGRID, 512, 0, stream>>>(aggb, xb, WT + 0 * 32768, b1l, h1, nullptr);
  agg_k<<<AGG_GRID, 256, 0, stream>>>(h1, rowptr, eidx, aggb);
  layer_k<<<LGRID, 512, 0, stream>>>(aggb, h1, WT + 1 * 32768, b2l, h2, nullptr);
  agg_k<<<AGG_GRID, 256, 0, stream>>>(h2, rowptr, eidx, aggb);
  layer_k<<<LGRID, 512, 0, stream>>>(aggb, h2, WT + 2 * 32768, b3l, nullptr, hg);

  final_k<<<GG, 128, 0, stream>>>(hg, root, x, Wnews, bnews,
                                  Wlin2, blin2, Wlin3, blin3, out);
}

// Round 16
// 195.766 us; speedup vs baseline: 1.2331x; 1.0714x over previous
//
#include <hip/hip_runtime.h>
#include <math.h>

#define NN 50000
#define EE 600000
#define GG 250
#define HH 128

// prep_k grid split
#define B_CVT  6250
#define B_W    384
#define B_ROOT 196
#define B_ZD   196
#define B_ZH   125

typedef __attribute__((ext_vector_type(8))) short s16x8;
typedef __attribute__((ext_vector_type(8))) unsigned short u16x8;
typedef __attribute__((ext_vector_type(4))) unsigned short u16x4;
typedef __attribute__((ext_vector_type(16))) signed char s8x16;
typedef __attribute__((ext_vector_type(4))) float f32x4;
typedef __attribute__((ext_vector_type(2))) float f32x2;

__device__ __forceinline__ float b2f(unsigned short u) {
  union { unsigned int i; float f; } v; v.i = ((unsigned int)u) << 16; return v.f;
}
__device__ __forceinline__ unsigned short f2b(float f) {
  union { float f; unsigned int i; } v; v.f = f;
  unsigned int x = v.i;
  unsigned int r = (x + 0x7FFFu + ((x >> 16) & 1u)) >> 16;   // RNE, finite inputs
  return (unsigned short)r;
}

// ---------- fused prep: cvt_x(bf16+fp8) | cvtW(frag layout) | root | zero-deg | zero-hg ----------
// WT2 layout: idx = L*32768 + w*4096 + m*2048 + kk*512 + lane*8 + j
__global__ __launch_bounds__(256) void prep_k(
    const float* __restrict__ x, unsigned short* __restrict__ xb,
    unsigned char* __restrict__ xq,
    const float* __restrict__ W0, const float* __restrict__ W1,
    const float* __restrict__ W2, const float* __restrict__ W3,
    const float* __restrict__ W4, const float* __restrict__ W5,
    unsigned short* __restrict__ WT,
    int* __restrict__ deg,
    const int* __restrict__ batch, int* __restrict__ root,
    float* __restrict__ hg) {
  int b = blockIdx.x, tid = threadIdx.x;
  if (b < B_CVT) {
    int i = b * 256 + tid;                       // x4 floats
    float4 v = *(const float4*)&x[i * 4];
    u16x4 o; o[0] = f2b(v.x); o[1] = f2b(v.y); o[2] = f2b(v.z); o[3] = f2b(v.w);
    *(u16x4*)&xb[i * 4] = o;
    int pk = __builtin_amdgcn_cvt_pk_fp8_f32(v.x, v.y, 0, false);
    pk = __builtin_amdgcn_cvt_pk_fp8_f32(v.z, v.w, pk, true);
    *(int*)&xq[i * 4] = pk;
  } else if (b < B_CVT + B_W) {
    int i = (b - B_CVT) * 256 + tid;             // 0..98303
    int j = i & 7, lane = (i >> 3) & 63, kk = (i >> 9) & 3;
    int m = (i >> 11) & 1, w = (i >> 12) & 7, L = i >> 15;
    int sel = L * 2 + m;
    const float* W = (sel == 0) ? W0 : (sel == 1) ? W1 : (sel == 2) ? W2
                     : (sel == 3) ? W3 : (sel == 4) ? W4 : W5;
    int col = w * 16 + (lane & 15);
    int k = kk * 32 + ((lane >> 4) & 3) * 8 + j;
    WT[i] = f2b(W[k * 128 + col]);
  } else if (b < B_CVT + B_W + B_ROOT) {
    int n = (b - B_CVT - B_W) * 256 + tid;
    if (n < NN) {
      int bg = batch[n];
      if (n == 0 || batch[n - 1] != bg) root[bg] = n;
    }
  } else if (b < B_CVT + B_W + B_ROOT + B_ZD) {
    int n = (b - B_CVT - B_W - B_ROOT) * 256 + tid;
    if (n < NN) deg[n] = 0;
  } else {
    int i = (b - B_CVT - B_W - B_ROOT - B_ZD) * 256 + tid;   // < 32000
    hg[i] = 0.f;
  }
}

// ---------- histogram ----------
__global__ void hist_k(const int* __restrict__ dst, int* __restrict__ deg) {
  int e = blockIdx.x * 256 + threadIdx.x;
  if (e < EE) atomicAdd(&deg[dst[e]], 1);
}

// ---------- scan, phase 1 ----------
__global__ __launch_bounds__(1024) void scan1_k(const int* __restrict__ deg,
                                                int* __restrict__ excl,
                                                int* __restrict__ bsum) {
  __shared__ int sums[16];
  int tid = threadIdx.x;
  int i = blockIdx.x * 1024 + tid;
  int v = (i < NN) ? deg[i] : 0;
  int lane = tid & 63, wid = tid >> 6;
  int x = v;
  #pragma unroll
  for (int d = 1; d < 64; d <<= 1) { int y = __shfl_up(x, d); if (lane >= d) x += y; }
  if (lane == 63) sums[wid] = x;
  __syncthreads();
  if (wid == 0) {
    int s = (lane < 16) ? sums[lane] : 0;
    #pragma unroll
    for (int d = 1; d < 16; d <<= 1) { int y = __shfl_up(s, d); if (lane >= d) s += y; }
    if (lane < 16) sums[lane] = s;
  }
  __syncthreads();
  int ex = (wid ? sums[wid - 1] : 0) + x - v;
  if (i < NN) excl[i] = ex;
  if (tid == 1023) bsum[blockIdx.x] = sums[15];
}

// ---------- scan, phase 2+3 fused ----------
__global__ __launch_bounds__(256) void scanB_k(const int* __restrict__ excl,
                                               const int* __restrict__ bsum,
                                               int* __restrict__ rowptr,
                                               int* __restrict__ wp) {
  __shared__ int sboff[64];
  int tid = threadIdx.x;
  if (tid < 64) {
    int v = (tid < 49) ? bsum[tid] : 0;
    int x = v;
    #pragma unroll
    for (int d = 1; d < 64; d <<= 1) { int y = __shfl_up(x, d); if (tid >= d) x += y; }
    sboff[tid] = x - v;
  }
  __syncthreads();
  int i = blockIdx.x * 256 + tid;
  if (i < NN) {
    int r = excl[i] + sboff[i >> 10];
    rowptr[i] = r; wp[i] = r;
  }
  if (i == 0) rowptr[NN] = EE;
}

__global__ void scatter_k(const int* __restrict__ src, const int* __restrict__ dst,
                          int* __restrict__ wp, int* __restrict__ eidx) {
  int e = blockIdx.x * 256 + threadIdx.x;
  if (e < EE) {
    int p = atomicAdd(&wp[dst[e]], 1);
    eidx[p] = src[e];
  }
}

// ---------- fused layer: fp8 gather-mean -> LDS, MFMA, L2norm, relu, dual store ----------
// 512 threads / 8 waves / 64 rows. Gather reads fp8 e4m3 rows (128B, no scale);
// self path reads bf16. Outputs bf16 (next self) + fp8 (next gather).
// Layer 3: hout=nullptr -> pool only, no stores.
__global__ __launch_bounds__(512) void layer_k(
    const unsigned short* __restrict__ hb,
    const unsigned char* __restrict__ hq,
    const int* __restrict__ rowptr, const int* __restrict__ eidx,
    const unsigned short* __restrict__ WT2, const float* __restrict__ bl,
    unsigned short* __restrict__ hout, unsigned char* __restrict__ houtq,
    float* __restrict__ hgmax) {
  __shared__ unsigned short sAgg[64 * 128];   // 16 KB (reused as bf16 out)
  __shared__ unsigned short sH[64 * 128];     // 16 KB (reused as fp8 out)
  __shared__ float sred[8][64];
  __shared__ float sinv[64];
  int tid = threadIdx.x;
  int r0 = blockIdx.x * 64;
  int lane = tid & 63, w = tid >> 6;
  int l16 = lane & 15, hi = lane >> 4;
  bool doout = (hout != nullptr);

  // ---- weights & bias (issue first) ----
  s16x8 wf[8];
  #pragma unroll
  for (int f = 0; f < 8; ++f)
    wf[f] = *(const s16x8*)&WT2[w * 4096 + f * 512 + lane * 8];
  float bb = bl[w * 16 + l16];

  // ---- gather phase: 32 groups of 16 lanes, 2 nodes each (fp8 rows, 8B/lane) ----
  {
    int gid = tid >> 4, gl = tid & 15;
    #pragma unroll 1
    for (int s = 0; s < 2; ++s) {
      int rl = gid * 2 + s;
      int node = r0 + rl; if (node > NN - 1) node = NN - 1;
      int st = rowptr[node], en = rowptr[node + 1];
      u16x8 own = *(const u16x8*)&hb[node * 128 + gl * 8];
      *(u16x8*)&sH[rl * 128 + ((gl ^ (rl & 7)) * 8)] = own;
      float acc[8] = {0.f, 0.f, 0.f, 0.f, 0.f, 0.f, 0.f, 0.f};
      for (int e = st; e < en; e += 4) {
        int e1 = e + 1 < en ? e + 1 : en - 1;
        int e2 = e + 2 < en ? e + 2 : en - 1;
        int e3 = e + 3 < en ? e + 3 : en - 1;
        int s0 = eidx[e], s1 = eidx[e1], s2 = eidx[e2], s3 = eidx[e3];
        uint2 v0 = *(const uint2*)&hq[s0 * 128 + gl * 8];
        uint2 v1 = *(const uint2*)&hq[s1 * 128 + gl * 8];
        uint2 v2 = *(const uint2*)&hq[s2 * 128 + gl * 8];
        uint2 v3 = *(const uint2*)&hq[s3 * 128 + gl * 8];
        float m1 = (e + 1 < en) ? 1.f : 0.f;
        float m2 = (e + 2 < en) ? 1.f : 0.f;
        float m3 = (e + 3 < en) ? 1.f : 0.f;
        {
          f32x2 p0 = __builtin_amdgcn_cvt_pk_f32_fp8(v0.x, false);
          f32x2 p1 = __builtin_amdgcn_cvt_pk_f32_fp8(v0.x, true);
          f32x2 p2 = __builtin_amdgcn_cvt_pk_f32_fp8(v0.y, false);
          f32x2 p3 = __builtin_amdgcn_cvt_pk_f32_fp8(v0.y, true);
          acc[0] += p0.x; acc[1] += p0.y; acc[2] += p1.x; acc[3] += p1.y;
          acc[4] += p2.x; acc[5] += p2.y; acc[6] += p3.x; acc[7] += p3.y;
        }
        {
          f32x2 p0 = __builtin_amdgcn_cvt_pk_f32_fp8(v1.x, false);
          f32x2 p1 = __builtin_amdgcn_cvt_pk_f32_fp8(v1.x, true);
          f32x2 p2 = __builtin_amdgcn_cvt_pk_f32_fp8(v1.y, false);
          f32x2 p3 = __builtin_amdgcn_cvt_pk_f32_fp8(v1.y, true);
          acc[0] = fmaf(m1, p0.x, acc[0]); acc[1] = fmaf(m1, p0.y, acc[1]);
          acc[2] = fmaf(m1, p1.x, acc[2]); acc[3] = fmaf(m1, p1.y, acc[3]);
          acc[4] = fmaf(m1, p2.x, acc[4]); acc[5] = fmaf(m1, p2.y, acc[5]);
          acc[6] = fmaf(m1, p3.x, acc[6]); acc[7] = fmaf(m1, p3.y, acc[7]);
        }
        {
          f32x2 p0 = __builtin_amdgcn_cvt_pk_f32_fp8(v2.x, false);
          f32x2 p1 = __builtin_amdgcn_cvt_pk_f32_fp8(v2.x, true);
          f32x2 p2 = __builtin_amdgcn_cvt_pk_f32_fp8(v2.y, false);
          f32x2 p3 = __builtin_amdgcn_cvt_pk_f32_fp8(v2.y, true);
          acc[0] = fmaf(m2, p0.x, acc[0]); acc[1] = fmaf(m2, p0.y, acc[1]);
          acc[2] = fmaf(m2, p1.x, acc[2]); acc[3] = fmaf(m2, p1.y, acc[3]);
          acc[4] = fmaf(m2, p2.x, acc[4]); acc[5] = fmaf(m2, p2.y, acc[5]);
          acc[6] = fmaf(m2, p3.x, acc[6]); acc[7] = fmaf(m2, p3.y, acc[7]);
        }
        {
          f32x2 p0 = __builtin_amdgcn_cvt_pk_f32_fp8(v3.x, false);
          f32x2 p1 = __builtin_amdgcn_cvt_pk_f32_fp8(v3.x, true);
          f32x2 p2 = __builtin_amdgcn_cvt_pk_f32_fp8(v3.y, false);
          f32x2 p3 = __builtin_amdgcn_cvt_pk_f32_fp8(v3.y, true);
          acc[0] = fmaf(m3, p0.x, acc[0]); acc[1] = fmaf(m3, p0.y, acc[1]);
          acc[2] = fmaf(m3, p1.x, acc[2]); acc[3] = fmaf(m3, p1.y, acc[3]);
          acc[4] = fmaf(m3, p2.x, acc[4]); acc[5] = fmaf(m3, p2.y, acc[5]);
          acc[6] = fmaf(m3, p3.x, acc[6]); acc[7] = fmaf(m3, p3.y, acc[7]);
        }
      }
      int cnt = en - st;
      float inv = 1.f / (float)(cnt > 0 ? cnt : 1);
      u16x8 o;
      #pragma unroll
      for (int j = 0; j < 8; ++j) o[j] = f2b(acc[j] * inv);
      *(u16x8*)&sAgg[rl * 128 + ((gl ^ (rl & 7)) * 8)] = o;
    }
  }
  __syncthreads();

  // ---- MFMA: 4 row-tiles x this wave's col-tile ----
  f32x4 acc[4];
  #pragma unroll
  for (int rt = 0; rt < 4; ++rt) acc[rt] = (f32x4){0.f, 0.f, 0.f, 0.f};
  #pragma unroll
  for (int kk = 0; kk < 4; ++kk) {
    int au = ((kk * 4 + hi) ^ (l16 & 7)) * 8;
    #pragma unroll
    for (int rt = 0; rt < 4; ++rt) {
      s16x8 a = *(const s16x8*)&sAgg[(rt * 16 + l16) * 128 + au];
      s16x8 h = *(const s16x8*)&sH[(rt * 16 + l16) * 128 + au];
      acc[rt] = __builtin_amdgcn_mfma_f32_16x16x32_bf16(a, wf[kk], acc[rt], 0, 0, 0);
      acc[rt] = __builtin_amdgcn_mfma_f32_16x16x32_bf16(h, wf[4 + kk], acc[rt], 0, 0, 0);
    }
  }

  // ---- bias + partial row-norm (this wave's 16 cols) ----
  float v[4][4];
  #pragma unroll
  for (int rt = 0; rt < 4; ++rt) {
    float ss[4];
    #pragma unroll
    for (int i = 0; i < 4; ++i) {
      float t = acc[rt][i] + bb;
      v[rt][i] = t;
      ss[i] = t * t;
    }
    #pragma unroll
    for (int m = 1; m < 16; m <<= 1) {
      #pragma unroll
      for (int i = 0; i < 4; ++i) ss[i] += __shfl_xor(ss[i], m);
    }
    if (l16 == 0) {
      #pragma unroll
      for (int i = 0; i < 4; ++i) sred[w][rt * 16 + hi * 4 + i] = ss[i];
    }
  }
  __syncthreads();
  if (tid < 64) {
    float s = 0.f;
    #pragma unroll
    for (int ww = 0; ww < 8; ++ww) s += sred[ww][tid];
    sinv[tid] = 1.f / fmaxf(sqrtf(s), 1e-12f);
  }
  __syncthreads();

  // ---- relu + dual LDS store + fused pool (layer 3) ----
  unsigned char* sQ = (unsigned char*)sH;
  #pragma unroll
  for (int rt = 0; rt < 4; ++rt) {
    float vm = 0.f;
    #pragma unroll
    for (int i = 0; i < 4; ++i) {
      int row = rt * 16 + hi * 4 + i;
      float r = fmaxf(v[rt][i] * sinv[row], 0.f);
      vm = fmaxf(vm, r);
      if (doout) {
        sAgg[row * 128 + ((w ^ (row & 7)) * 16) + l16] = f2b(r);
        int e8 = __builtin_amdgcn_cvt_pk_fp8_f32(r, r, 0, false);
        sQ[row * 128 + ((w ^ (row & 7)) * 16) + l16] = (unsigned char)(e8 & 0xFF);
      }
    }
    if (hgmax) {
      int rsb = r0 + rt * 16 + hi * 4;          // 4-row strips never cross graphs
      if (rsb < NN)
        atomicMax((int*)&hgmax[(rsb / 200) * 128 + w * 16 + l16], __float_as_int(vm));
    }
  }
  if (!doout) return;
  __syncthreads();

  // ---- coalesced read-back & store ----
  {
    int rr = tid >> 3, q = tid & 7;
    int row = r0 + rr;
    if (row < NN) {
      int sb = rr * 128 + ((q ^ (rr & 7)) * 16);
      u16x8 p0 = *(const u16x8*)&sAgg[sb];
      u16x8 p1 = *(const u16x8*)&sAgg[sb + 8];
      *(u16x8*)&hout[row * 128 + q * 16] = p0;
      *(u16x8*)&hout[row * 128 + q * 16 + 8] = p1;
      s8x16 pq = *(const s8x16*)&sQ[sb];
      *(s8x16*)&houtq[row * 128 + q * 16] = pq;
    }
  }
}

// ---------- final: news + lin2 + lin3 + sigmoid ----------
__global__ __launch_bounds__(128) void final_k(
    const float* __restrict__ hg, const int* __restrict__ root,
    const float* __restrict__ x,
    const float* __restrict__ Wn, const float* __restrict__ bn,
    const float* __restrict__ W2, const float* __restrict__ b2,
    const float* __restrict__ W3, const float* __restrict__ b3,
    float* __restrict__ out) {
  __shared__ float hgr[128];
  __shared__ float xr[128];
  __shared__ float red[2];
  int g = blockIdx.x, j = threadIdx.x;
  int rt = root[g];
  hgr[j] = hg[g * HH + j];
  xr[j] = x[rt * HH + j];
  __syncthreads();
  float acc2 = b2[j];
  float accn = bn[j];
  for (int k = 0; k < 128; ++k) {
    acc2 += hgr[k] * W2[k * HH + j];
    accn += xr[k] * Wn[k * HH + j];
  }
  float c = fmaxf(acc2, 0.f) * W3[j] + fmaxf(accn, 0.f) * W3[HH + j];
  #pragma unroll
  for (int d = 1; d < 64; d <<= 1) c += __shfl_xor(c, d);
  if ((j & 63) == 0) red[j >> 6] = c;
  __syncthreads();
  if (j == 0) out[g] = 1.f / (1.f + expf(-(red[0] + red[1] + b3[0])));
}

extern "C" void kernel_launch(void* const* d_in, const int* in_sizes, int n_in,
                              void* d_out, int out_size, void* d_ws, size_t ws_size,
                              hipStream_t stream) {
  const float* x     = (const float*)d_in[0];
  const int*   adj   = (const int*)d_in[1];
  const int*   batch = (const int*)d_in[2];
  const float *W1l = (const float*)d_in[3],  *b1l = (const float*)d_in[4],  *W1r = (const float*)d_in[5];
  const float *W2l = (const float*)d_in[6],  *b2l = (const float*)d_in[7],  *W2r = (const float*)d_in[8];
  const float *W3l = (const float*)d_in[9],  *b3l = (const float*)d_in[10], *W3r = (const float*)d_in[11];
  const float *Wnews = (const float*)d_in[12], *bnews = (const float*)d_in[13];
  const float *Wlin2 = (const float*)d_in[14], *blin2 = (const float*)d_in[15];
  const float *Wlin3 = (const float*)d_in[16], *blin3 = (const float*)d_in[17];
  float* out = (float*)d_out;

  const int* srcp = adj;
  const int* dstp = adj + EE;

  char* ws = (char*)d_ws;
  size_t off = 0;
  auto alloc = [&](size_t bytes) -> void* {
    void* p = ws + off;
    off = (off + bytes + 255) & ~(size_t)255;
    return p;
  };
  int*   deg    = (int*)alloc(sizeof(int) * NN);
  int*   excl   = (int*)alloc(sizeof(int) * NN);
  int*   bsum   = (int*)alloc(sizeof(int) * 64);
  int*   rowptr = (int*)alloc(sizeof(int) * (NN + 1));
  int*   wp     = (int*)alloc(sizeof(int) * NN);
  int*   root   = (int*)alloc(sizeof(int) * GG);
  int*   eidx   = (int*)alloc(sizeof(int) * EE);
  unsigned short* WT = (unsigned short*)alloc(sizeof(short) * 6 * 128 * 128);
  unsigned short* xb = (unsigned short*)alloc(sizeof(short) * NN * HH);
  unsigned short* h1 = (unsigned short*)alloc(sizeof(short) * NN * HH);
  unsigned short* h2 = (unsigned short*)alloc(sizeof(short) * NN * HH);
  unsigned char* xq = (unsigned char*)alloc(NN * HH);
  unsigned char* q1 = (unsigned char*)alloc(NN * HH);
  unsigned char* q2 = (unsigned char*)alloc(NN * HH);
  float* hg = (float*)alloc(sizeof(float) * GG * HH);
  (void)ws_size; (void)n_in; (void)in_sizes; (void)out_size;

  prep_k<<<B_CVT + B_W + B_ROOT + B_ZD + B_ZH, 256, 0, stream>>>(
      x, xb, xq, W1l, W1r, W2l, W2r, W3l, W3r, WT, deg, batch, root, hg);
  hist_k<<<(EE + 255) / 256, 256, 0, stream>>>(dstp, deg);
  scan1_k<<<(NN + 1023) / 1024, 1024, 0, stream>>>(deg, excl, bsum);
  scanB_k<<<(NN + 255) / 256, 256, 0, stream>>>(excl, bsum, rowptr, wp);
  scatter_k<<<(EE + 255) / 256, 256, 0, stream>>>(srcp, dstp, wp, eidx);

  const int LGRID = (NN + 63) / 64;          // 782

  layer_k<<<LGRID, 512, 0, stream>>>(xb, xq, rowptr, eidx,
                                     WT + 0 * 32768, b1l, h1, q1, nullptr);
  layer_k<<<LGRID, 512, 0, stream>>>(h1, q1, rowptr, eidx,
                                     WT + 1 * 32768, b2l, h2, q2, nullptr);
  layer_k<<<LGRID, 512, 0, stream>>>(h2, q2, rowptr, eidx,
                                     WT + 2 * 32768, b3l, nullptr, nullptr, hg);

  final_k<<<GG, 128, 0, stream>>>(hg, root, x, Wnews, bnews,
                                  Wlin2, blin2, Wlin3, blin3, out);
}